// Round 1
// baseline (3375.716 us; speedup 1.0000x reference)
//
#include <hip/hip_runtime.h>

// QMixer fused kernel — fp32 baseline (round 1).
// B = 32768 rows; per row:
//   h1 = relu(s@w1_0^T + b1_0)            [256]
//   w1 = |h1@w1_2^T + b1_2|               [2048] -> [32 agents][64 embed]
//   b1 = s@hb_w^T + hb_b                  [64]
//   hidden = elu(q@w1 + b1)               [64]
//   hf = relu(s@wf_0^T + bf_0)            [256]
//   wfin = |hf@wf_2^T + bf_2|             [64]
//   v = relu(s@v0_w^T + v0_b)@v2_w^T+v2_b [1]
//   y = hidden.wfin + v
// One block = 32 rows, 512 threads. s/h1/hf staged in LDS (padded strides).

#define BTOT   32768
#define ROWS   32
#define SDIM   512
#define HDIM   256
#define EDIM   64
#define AGENTS 32

#define SPAD 516   // 512+4: rows rotate banks by 4 -> b128 reads conflict-free
#define HPAD 260   // 256+4
#define QPAD 33
#define BPAD 65

// 8 simultaneous dot products of length KC*64 against one LDS row.
// LDS chunk (64 floats) cached in registers, reused across the 8 columns.
template<int KC>
__device__ __forceinline__ void dot8(const float* const* wr, const float* srow, float* acc)
{
#pragma unroll
  for (int u = 0; u < 8; u++) acc[u] = 0.f;
#pragma unroll 1
  for (int kc = 0; kc < KC; kc++) {
    float4 ch[16];
    const float* sp = srow + kc * 64;
#pragma unroll
    for (int m = 0; m < 16; m++) ch[m] = *(const float4*)(sp + m * 4);
#pragma unroll
    for (int u = 0; u < 8; u++) {
      const float4* wp = (const float4*)(wr[u] + kc * 64);
      float a = acc[u];
#pragma unroll
      for (int m = 0; m < 16; m++) {
        float4 wv = wp[m];
        a = fmaf(ch[m].x, wv.x, a);
        a = fmaf(ch[m].y, wv.y, a);
        a = fmaf(ch[m].z, wv.z, a);
        a = fmaf(ch[m].w, wv.w, a);
      }
      acc[u] = a;
    }
  }
}

__global__ __launch_bounds__(512, 2) void qmix_fused(
    const float* __restrict__ agent_qs, const float* __restrict__ states,
    const float* __restrict__ w1_0, const float* __restrict__ b1_0,
    const float* __restrict__ w1_2, const float* __restrict__ b1_2,
    const float* __restrict__ wf_0, const float* __restrict__ bf_0,
    const float* __restrict__ wf_2, const float* __restrict__ bf_2,
    const float* __restrict__ hb_w, const float* __restrict__ hb_b,
    const float* __restrict__ v0_w, const float* __restrict__ v0_b,
    const float* __restrict__ v2_w, const float* __restrict__ v2_b,
    float* __restrict__ out)
{
  __shared__ float st [ROWS * SPAD];   // 66.0 KB
  __shared__ float h1t[ROWS * HPAD];   // 33.3 KB
  __shared__ float hft[ROWS * HPAD];   // 33.3 KB
  __shared__ float qt [ROWS * QPAD];   //  4.2 KB
  __shared__ float b1t[ROWS * BPAD];   //  8.3 KB
  __shared__ float vpart[ROWS * 16];   //  2.0 KB
  __shared__ float ypart[ROWS * 16];   //  2.0 KB

  const int t   = threadIdx.x;
  const int bid = blockIdx.x;
  const long base_row = (long)bid * ROWS;

  // ---- phase 0: stage s tile and q tile ----
  {
    const float4* gs = (const float4*)(states + base_row * SDIM);
#pragma unroll
    for (int v = 0; v < 8; v++) {
      int n    = v * 512 + t;     // 4096 float4 in tile
      int row  = n >> 7;          // 128 float4 per row
      int col4 = n & 127;
      float4 val = gs[n];
      *(float4*)(&st[row * SPAD + col4 * 4]) = val;
    }
    if (t < 256) {
      const float4* gq = (const float4*)(agent_qs + base_row * AGENTS);
      float4 qv = gq[t];
      int row = t >> 3;
      int a   = (t & 7) * 4;
      qt[row * QPAD + a + 0] = qv.x;
      qt[row * QPAD + a + 1] = qv.y;
      qt[row * QPAD + a + 2] = qv.z;
      qt[row * QPAD + a + 3] = qv.w;
    }
  }
  __syncthreads();

  const int r = t & 31;   // row in tile
  const int g = t >> 5;   // column group, 0..15

  // ---- phase 1: hypernet layer 0 — 640 output cols over K=512 ----
  // cols 0..255 -> h1 (w1_0), 256..511 -> hf (wf_0), 512..575 -> b1 (hb_w),
  // 576..639 -> v hidden (v0_w, folded into vsum with v2_w).
  {
    const float* srow = &st[r * SPAD];
    float vsum = 0.f;
#pragma unroll 1
    for (int cb = 0; cb < 5; cb++) {
      const float* wr[8];
#pragma unroll
      for (int u = 0; u < 8; u++) {
        int col = (cb * 8 + u) * 16 + g;
        const float* bse; int lrow;
        if (col < 256)      { bse = w1_0; lrow = col; }
        else if (col < 512) { bse = wf_0; lrow = col - 256; }
        else if (col < 576) { bse = hb_w; lrow = col - 512; }
        else                { bse = v0_w; lrow = col - 576; }
        wr[u] = bse + lrow * SDIM;
      }
      float acc[8];
      dot8<8>(wr, srow, acc);
#pragma unroll
      for (int u = 0; u < 8; u++) {
        int col = (cb * 8 + u) * 16 + g;
        if (col < 256) {
          h1t[r * HPAD + col] = fmaxf(acc[u] + b1_0[col], 0.f);
        } else if (col < 512) {
          int c2 = col - 256;
          hft[r * HPAD + c2] = fmaxf(acc[u] + bf_0[c2], 0.f);
        } else if (col < 576) {
          int eb = col - 512;
          b1t[r * BPAD + eb] = acc[u] + hb_b[eb];
        } else {
          int ev = col - 576;
          vsum += fmaxf(acc[u] + v0_b[ev], 0.f) * v2_w[ev];
        }
      }
    }
    vpart[r * 16 + g] = vsum;
  }
  __syncthreads();

  // ---- phase 2: w1 GEMM fused with |.|, q-contraction, wfin, elu, y ----
  {
    const float* h1row = &h1t[r * HPAD];
    const float* hfrow = &hft[r * HPAD];
    const float* qrow  = &qt [r * QPAD];
    const float* b1row = &b1t[r * BPAD];
    float yp = 0.f;
#pragma unroll 1
    for (int i = 0; i < 4; i++) {
      int e = g * 4 + i;
      float hid = 0.f;
#pragma unroll 1
      for (int ab = 0; ab < 4; ab++) {
        const float* wr[8];
#pragma unroll
        for (int u = 0; u < 8; u++) wr[u] = w1_2 + ((ab * 8 + u) * EDIM + e) * HDIM;
        float acc[8];
        dot8<4>(wr, h1row, acc);
#pragma unroll
        for (int u = 0; u < 8; u++) {
          int a2 = ab * 8 + u;
          int j  = a2 * EDIM + e;
          hid = fmaf(qrow[a2], fabsf(acc[u] + b1_2[j]), hid);
        }
      }
      // w_final column e: dot(hf, wf_2[e]) over K=256
      float wa = 0.f;
      const float4* wp = (const float4*)(wf_2 + e * HDIM);
#pragma unroll 1
      for (int m = 0; m < 16; m++) {
#pragma unroll
        for (int mm = 0; mm < 4; mm++) {
          float4 wv = wp[m * 4 + mm];
          float4 hv = *(const float4*)(hfrow + (m * 4 + mm) * 4);
          wa = fmaf(hv.x, wv.x, wa);
          wa = fmaf(hv.y, wv.y, wa);
          wa = fmaf(hv.z, wv.z, wa);
          wa = fmaf(hv.w, wv.w, wa);
        }
      }
      float wfv = fabsf(wa + bf_2[e]);
      float pre = hid + b1row[e];
      float hv2 = pre > 0.f ? pre : expm1f(pre);   // elu
      yp = fmaf(hv2, wfv, yp);
    }
    ypart[r * 16 + g] = yp;
  }
  __syncthreads();

  // ---- phase 3: reduce 16 partials per row, add v, write out ----
  if (t < ROWS) {
    float ysum = 0.f, vsum = 0.f;
#pragma unroll
    for (int k = 0; k < 16; k++) {
      ysum += ypart[t * 16 + k];
      vsum += vpart[t * 16 + k];
    }
    out[base_row + t] = ysum + vsum + v2_b[0];
  }
}

extern "C" void kernel_launch(void* const* d_in, const int* in_sizes, int n_in,
                              void* d_out, int out_size, void* d_ws, size_t ws_size,
                              hipStream_t stream) {
  qmix_fused<<<dim3(BTOT / ROWS), dim3(512), 0, stream>>>(
      (const float*)d_in[0],  (const float*)d_in[1],
      (const float*)d_in[2],  (const float*)d_in[3],
      (const float*)d_in[4],  (const float*)d_in[5],
      (const float*)d_in[6],  (const float*)d_in[7],
      (const float*)d_in[8],  (const float*)d_in[9],
      (const float*)d_in[10], (const float*)d_in[11],
      (const float*)d_in[12], (const float*)d_in[13],
      (const float*)d_in[14], (const float*)d_in[15],
      (float*)d_out);
}

// Round 2
// 354.161 us; speedup vs baseline: 9.5316x; 9.5316x over previous
//
#include <hip/hip_runtime.h>

// QMixer — round 2: MFMA bf16 restructure.
//   convert: weights -> bf16 in ws
//   gemm1:   [32768,512] @ [512,640]^T  (w1_0|wf_0|hb_w|v0_w concat) + bias/relu heads
//            -> hcat bf16 [B][512] (h1|hf), b1buf f32 [B][64], vbuf f32 [B]
//   gemm2:   per 64-row block: hidden = elu(sum_a q_a*|h1@w1_2a^T+b|) + b1;
//            wfin = |hf@wf_2^T+bf_2|; y = sum_e hidden*wfin + v + v2_b

#define BTOT 32768
#define SDIM 512
#define HD   256
#define EDIM 64
#define NAG  32

typedef short short8v __attribute__((ext_vector_type(8)));
typedef float f32x4  __attribute__((ext_vector_type(4)));

__device__ __forceinline__ unsigned short f2bf(float f) {
  unsigned int u = __float_as_uint(f);
  unsigned int r = (u + 0x7FFFu + ((u >> 16) & 1u)) >> 16;
  return (unsigned short)r;
}

__device__ __forceinline__ short8v ld_cvt8(const float* p) {
  float4 a = ((const float4*)p)[0];
  float4 b = ((const float4*)p)[1];
  short8v r;
  r[0] = (short)f2bf(a.x); r[1] = (short)f2bf(a.y);
  r[2] = (short)f2bf(a.z); r[3] = (short)f2bf(a.w);
  r[4] = (short)f2bf(b.x); r[5] = (short)f2bf(b.y);
  r[6] = (short)f2bf(b.z); r[7] = (short)f2bf(b.w);
  return r;
}

// ---------------- convert weights to bf16 ----------------
// W0cat [640][512] = w1_0(256) | wf_0(256) | hb_w(64) | v0_w(64); w12b [2048][256]; wf2b [64][256]
__global__ void qmix_convert(const float* __restrict__ w1_0, const float* __restrict__ wf_0,
                             const float* __restrict__ hb_w, const float* __restrict__ v0_w,
                             const float* __restrict__ w1_2, const float* __restrict__ wf_2,
                             unsigned short* __restrict__ W0cat, unsigned short* __restrict__ w12b,
                             unsigned short* __restrict__ wf2b) {
  int i = blockIdx.x * 256 + threadIdx.x;
  if (i < 327680) {
    float v;
    if (i < 131072)      v = w1_0[i];
    else if (i < 262144) v = wf_0[i - 131072];
    else if (i < 294912) v = hb_w[i - 262144];
    else                 v = v0_w[i - 294912];
    W0cat[i] = f2bf(v);
  } else if (i < 851968) {
    w12b[i - 327680] = f2bf(w1_2[i - 327680]);
  } else if (i < 868352) {
    wf2b[i - 851968] = f2bf(wf_2[i - 851968]);
  }
}

// ---------------- GEMM1: S[64,512] x W0cat[64cols,512]^T ----------------
// grid (10, 512): x = n-block (which 64-col slab), y = m-block (64 rows)
__global__ __launch_bounds__(256) void qmix_gemm1(
    const float* __restrict__ states, const unsigned short* __restrict__ W0cat,
    const float* __restrict__ b1_0, const float* __restrict__ bf_0,
    const float* __restrict__ hb_b, const float* __restrict__ v0_b,
    const float* __restrict__ v2_w,
    unsigned short* __restrict__ hcat, float* __restrict__ b1buf, float* __restrict__ vbuf) {
  const int nblk = blockIdx.x;           // 0..9
  const int r0   = blockIdx.y * 64;
  const int n0   = nblk * 64;
  const int wave = threadIdx.x >> 6;
  const int lane = threadIdx.x & 63;
  const int wr = wave >> 1, wc = wave & 1;
  const int lrow = lane & 15, lk = lane >> 4;

  __shared__ float spart[2][64];

  f32x4 acc[2][2];
#pragma unroll
  for (int i = 0; i < 2; i++)
#pragma unroll
    for (int j = 0; j < 2; j++) acc[i][j] = (f32x4){0.f, 0.f, 0.f, 0.f};

#pragma unroll 4
  for (int k0 = 0; k0 < SDIM; k0 += 32) {
    short8v af[2], bf[2];
#pragma unroll
    for (int i = 0; i < 2; i++) {
      int row = r0 + wr * 32 + i * 16 + lrow;
      af[i] = ld_cvt8(states + (size_t)row * SDIM + k0 + 8 * lk);
    }
#pragma unroll
    for (int j = 0; j < 2; j++) {
      int wrow = n0 + wc * 32 + j * 16 + lrow;
      bf[j] = *(const short8v*)(W0cat + (size_t)wrow * SDIM + k0 + 8 * lk);
    }
#pragma unroll
    for (int i = 0; i < 2; i++)
#pragma unroll
      for (int j = 0; j < 2; j++)
        acc[i][j] = __builtin_amdgcn_mfma_f32_16x16x32_bf16(af[i], bf[j], acc[i][j], 0, 0, 0);
  }

  // epilogue per n-slab
  if (nblk < 8) {
    const float* bias = (nblk < 4) ? b1_0 : bf_0;
    int cbase = (nblk < 4) ? nblk * 64 : (nblk - 4) * 64;
    int obase = (nblk < 4) ? 0 : 256;
#pragma unroll
    for (int j = 0; j < 2; j++) {
      int cl = wc * 32 + j * 16 + lrow;
      float bv = bias[cbase + cl];
#pragma unroll
      for (int i = 0; i < 2; i++) {
#pragma unroll
        for (int r = 0; r < 4; r++) {
          int row_l = wr * 32 + i * 16 + lk * 4 + r;
          float v = acc[i][j][r] + bv;
          v = fmaxf(v, 0.f);
          hcat[(size_t)(r0 + row_l) * SDIM + obase + cbase + cl] = f2bf(v);
        }
      }
    }
  } else if (nblk == 8) {
#pragma unroll
    for (int j = 0; j < 2; j++) {
      int cl = wc * 32 + j * 16 + lrow;
      float bv = hb_b[cl];
#pragma unroll
      for (int i = 0; i < 2; i++)
#pragma unroll
        for (int r = 0; r < 4; r++) {
          int row_l = wr * 32 + i * 16 + lk * 4 + r;
          b1buf[(size_t)(r0 + row_l) * EDIM + cl] = acc[i][j][r] + bv;
        }
    }
  } else {
    float rs[8];
#pragma unroll
    for (int x = 0; x < 8; x++) rs[x] = 0.f;
#pragma unroll
    for (int j = 0; j < 2; j++) {
      int cl = wc * 32 + j * 16 + lrow;
      float bv = v0_b[cl], wv = v2_w[cl];
#pragma unroll
      for (int i = 0; i < 2; i++)
#pragma unroll
        for (int r = 0; r < 4; r++) {
          float v = fmaxf(acc[i][j][r] + bv, 0.f);
          rs[i * 4 + r] = fmaf(v, wv, rs[i * 4 + r]);
        }
    }
#pragma unroll
    for (int m = 1; m < 16; m <<= 1)
#pragma unroll
      for (int x = 0; x < 8; x++) rs[x] += __shfl_xor(rs[x], m, 64);
    if (lrow == 0) {
#pragma unroll
      for (int i = 0; i < 2; i++)
#pragma unroll
        for (int r = 0; r < 4; r++)
          spart[wc][wr * 32 + i * 16 + lk * 4 + r] = rs[i * 4 + r];
    }
    __syncthreads();
    if (threadIdx.x < 64) vbuf[r0 + threadIdx.x] = spart[0][threadIdx.x] + spart[1][threadIdx.x];
  }
}

// ---------------- GEMM2: fused hypernet-2 + mix ----------------
__global__ __launch_bounds__(256) void qmix_gemm2(
    const unsigned short* __restrict__ hcat, const unsigned short* __restrict__ w12b,
    const unsigned short* __restrict__ wf2b, const float* __restrict__ agent_qs,
    const float* __restrict__ b1_2, const float* __restrict__ bf_2,
    const float* __restrict__ b1buf, const float* __restrict__ vbuf,
    const float* __restrict__ v2_b, float* __restrict__ out) {
  const int r0   = blockIdx.x * 64;
  const int wave = threadIdx.x >> 6;
  const int lane = threadIdx.x & 63;
  const int wr = wave >> 1, wc = wave & 1;
  const int lrow = lane & 15, lk = lane >> 4;

  __shared__ float q_lds[64 * 33];
  __shared__ float ypart[2][64];

  // stage q tile [64][32]
  {
    const float4* gq = (const float4*)(agent_qs + (size_t)r0 * NAG);
#pragma unroll
    for (int v = 0; v < 2; v++) {
      int idx = v * 256 + threadIdx.x;   // 0..511
      float4 qv = gq[idx];
      int row = idx >> 3, c4 = (idx & 7) * 4;
      q_lds[row * 33 + c4 + 0] = qv.x;
      q_lds[row * 33 + c4 + 1] = qv.y;
      q_lds[row * 33 + c4 + 2] = qv.z;
      q_lds[row * 33 + c4 + 3] = qv.w;
    }
  }
  __syncthreads();

  // hoist A fragments (h1 part, k=0..255) into registers
  short8v afr[2][8];
#pragma unroll
  for (int i = 0; i < 2; i++) {
    int grow = r0 + wr * 32 + i * 16 + lrow;
#pragma unroll
    for (int kf = 0; kf < 8; kf++)
      afr[i][kf] = *(const short8v*)(hcat + (size_t)grow * SDIM + kf * 32 + 8 * lk);
  }

  f32x4 hac[2][2];
#pragma unroll
  for (int i = 0; i < 2; i++)
#pragma unroll
    for (int j = 0; j < 2; j++) hac[i][j] = (f32x4){0.f, 0.f, 0.f, 0.f};

#pragma unroll 1
  for (int a = 0; a < NAG; a++) {
    f32x4 T[2][2];
#pragma unroll
    for (int i = 0; i < 2; i++)
#pragma unroll
      for (int j = 0; j < 2; j++) T[i][j] = (f32x4){0.f, 0.f, 0.f, 0.f};
#pragma unroll
    for (int kf = 0; kf < 8; kf++) {
      short8v bf[2];
#pragma unroll
      for (int j = 0; j < 2; j++) {
        int wrow = a * 64 + wc * 32 + j * 16 + lrow;
        bf[j] = *(const short8v*)(w12b + (size_t)wrow * HD + kf * 32 + 8 * lk);
      }
#pragma unroll
      for (int i = 0; i < 2; i++)
#pragma unroll
        for (int j = 0; j < 2; j++)
          T[i][j] = __builtin_amdgcn_mfma_f32_16x16x32_bf16(afr[i][kf], bf[j], T[i][j], 0, 0, 0);
    }
    float bb[2];
#pragma unroll
    for (int j = 0; j < 2; j++) bb[j] = b1_2[a * 64 + wc * 32 + j * 16 + lrow];
    float qv[2][4];
#pragma unroll
    for (int i = 0; i < 2; i++)
#pragma unroll
      for (int r = 0; r < 4; r++)
        qv[i][r] = q_lds[(wr * 32 + i * 16 + lk * 4 + r) * 33 + a];
#pragma unroll
    for (int i = 0; i < 2; i++)
#pragma unroll
      for (int j = 0; j < 2; j++)
#pragma unroll
        for (int r = 0; r < 4; r++)
          hac[i][j][r] = fmaf(qv[i][r], fabsf(T[i][j][r] + bb[j]), hac[i][j][r]);
  }

  // wfin = |hf @ wf_2^T + bf_2|  (hf = hcat k=256..511)
  f32x4 wfa[2][2];
#pragma unroll
  for (int i = 0; i < 2; i++)
#pragma unroll
    for (int j = 0; j < 2; j++) wfa[i][j] = (f32x4){0.f, 0.f, 0.f, 0.f};
#pragma unroll
  for (int kf = 0; kf < 8; kf++) {
    short8v af2[2], bf2v[2];
#pragma unroll
    for (int i = 0; i < 2; i++) {
      int grow = r0 + wr * 32 + i * 16 + lrow;
      af2[i] = *(const short8v*)(hcat + (size_t)grow * SDIM + 256 + kf * 32 + 8 * lk);
    }
#pragma unroll
    for (int j = 0; j < 2; j++) {
      int wrow = wc * 32 + j * 16 + lrow;
      bf2v[j] = *(const short8v*)(wf2b + (size_t)wrow * HD + kf * 32 + 8 * lk);
    }
#pragma unroll
    for (int i = 0; i < 2; i++)
#pragma unroll
      for (int j = 0; j < 2; j++)
        wfa[i][j] = __builtin_amdgcn_mfma_f32_16x16x32_bf16(af2[i], bf2v[j], wfa[i][j], 0, 0, 0);
  }

  // epilogue: elu(hid + b1) * wfin, row-sum over e
  float ys[8];
#pragma unroll
  for (int x = 0; x < 8; x++) ys[x] = 0.f;
#pragma unroll
  for (int i = 0; i < 2; i++) {
#pragma unroll
    for (int r = 0; r < 4; r++) {
      int row_l = wr * 32 + i * 16 + lk * 4 + r;
      int grow = r0 + row_l;
#pragma unroll
      for (int j = 0; j < 2; j++) {
        int e = wc * 32 + j * 16 + lrow;
        float pre = hac[i][j][r] + b1buf[(size_t)grow * EDIM + e];
        float h = pre > 0.f ? pre : expm1f(pre);
        float wf = fabsf(wfa[i][j][r] + bf_2[e]);
        ys[i * 4 + r] = fmaf(h, wf, ys[i * 4 + r]);
      }
    }
  }
#pragma unroll
  for (int m = 1; m < 16; m <<= 1)
#pragma unroll
    for (int x = 0; x < 8; x++) ys[x] += __shfl_xor(ys[x], m, 64);
  if (lrow == 0) {
#pragma unroll
    for (int i = 0; i < 2; i++)
#pragma unroll
      for (int r = 0; r < 4; r++)
        ypart[wc][wr * 32 + i * 16 + lk * 4 + r] = ys[i * 4 + r];
  }
  __syncthreads();
  if (threadIdx.x < 64) {
    int grow = r0 + threadIdx.x;
    out[grow] = ypart[0][threadIdx.x] + ypart[1][threadIdx.x] + vbuf[grow] + v2_b[0];
  }
}

extern "C" void kernel_launch(void* const* d_in, const int* in_sizes, int n_in,
                              void* d_out, int out_size, void* d_ws, size_t ws_size,
                              hipStream_t stream) {
  const float* agent_qs = (const float*)d_in[0];
  const float* states   = (const float*)d_in[1];
  const float* w1_0 = (const float*)d_in[2];
  const float* b1_0 = (const float*)d_in[3];
  const float* w1_2 = (const float*)d_in[4];
  const float* b1_2 = (const float*)d_in[5];
  const float* wf_0 = (const float*)d_in[6];
  const float* bf_0 = (const float*)d_in[7];
  const float* wf_2 = (const float*)d_in[8];
  const float* bf_2 = (const float*)d_in[9];
  const float* hb_w = (const float*)d_in[10];
  const float* hb_b = (const float*)d_in[11];
  const float* v0_w = (const float*)d_in[12];
  const float* v0_b = (const float*)d_in[13];
  const float* v2_w = (const float*)d_in[14];
  const float* v2_b = (const float*)d_in[15];

  char* ws = (char*)d_ws;
  unsigned short* hcat  = (unsigned short*)ws;                  // 33,554,432 B
  float*          b1buf = (float*)(ws + 33554432);              //  8,388,608 B
  float*          vbuf  = (float*)(ws + 41943040);              //    131,072 B
  unsigned short* W0cat = (unsigned short*)(ws + 42074112);     //    655,360 B
  unsigned short* w12b  = (unsigned short*)(ws + 42729472);     //  1,048,576 B
  unsigned short* wf2b  = (unsigned short*)(ws + 43778048);     //     32,768 B

  qmix_convert<<<3392, 256, 0, stream>>>(w1_0, wf_0, hb_w, v0_w, w1_2, wf_2, W0cat, w12b, wf2b);
  qmix_gemm1<<<dim3(10, 512), 256, 0, stream>>>(states, W0cat, b1_0, bf_0, hb_b, v0_b, v2_w,
                                                hcat, b1buf, vbuf);
  qmix_gemm2<<<512, 256, 0, stream>>>(hcat, w12b, wf2b, agent_qs, b1_2, bf_2, b1buf, vbuf,
                                      v2_b, (float*)d_out);
}

// Round 3
// 157.164 us; speedup vs baseline: 21.4789x; 2.2534x over previous
//
#include <hip/hip_runtime.h>

// QMixer — round 3.
// gemm1: one block = 64 rows x ALL 640 cols (states read once, bf16-converted
//        into XOR-swizzled LDS once per block; B register-double-buffered from L2).
// gemm2: LDS double-buffered w1_2 staging (reg-stage + swizzled ds_write,
//        one barrier per agent), MFMA from swizzled LDS.

#define BTOT 32768
#define SDIM 512
#define HD   256
#define EDIM 64
#define NAG  32

typedef short short8v __attribute__((ext_vector_type(8)));
typedef short short4v __attribute__((ext_vector_type(4)));
typedef float f32x4  __attribute__((ext_vector_type(4)));

__device__ __forceinline__ unsigned short f2bf(float f) {
  unsigned int u = __float_as_uint(f);
  unsigned int r = (u + 0x7FFFu + ((u >> 16) & 1u)) >> 16;
  return (unsigned short)r;
}

__device__ __forceinline__ short4v cvt4(float4 a) {
  short4v r;
  r[0] = (short)f2bf(a.x); r[1] = (short)f2bf(a.y);
  r[2] = (short)f2bf(a.z); r[3] = (short)f2bf(a.w);
  return r;
}

// ---------------- convert weights to bf16 ----------------
__global__ void qmix_convert(const float* __restrict__ w1_0, const float* __restrict__ wf_0,
                             const float* __restrict__ hb_w, const float* __restrict__ v0_w,
                             const float* __restrict__ w1_2, const float* __restrict__ wf_2,
                             unsigned short* __restrict__ W0cat, unsigned short* __restrict__ w12b,
                             unsigned short* __restrict__ wf2b) {
  int i = blockIdx.x * 256 + threadIdx.x;
  if (i < 327680) {
    float v;
    if (i < 131072)      v = w1_0[i];
    else if (i < 262144) v = wf_0[i - 131072];
    else if (i < 294912) v = hb_w[i - 262144];
    else                 v = v0_w[i - 294912];
    W0cat[i] = f2bf(v);
  } else if (i < 851968) {
    w12b[i - 327680] = f2bf(w1_2[i - 327680]);
  } else if (i < 868352) {
    wf2b[i - 851968] = f2bf(wf_2[i - 851968]);
  }
}

// ---------------- GEMM1: 64 rows x 640 cols per block ----------------
// 512 threads = 8 waves as 2(row) x 4(col); wave tile 32 x 160.
__global__ __launch_bounds__(512, 2) void qmix_gemm1(
    const float* __restrict__ states, const unsigned short* __restrict__ W0cat,
    const float* __restrict__ b1_0, const float* __restrict__ bf_0,
    const float* __restrict__ hb_b, const float* __restrict__ v0_b,
    const float* __restrict__ v2_w,
    unsigned short* __restrict__ hcat, float* __restrict__ b1buf, float* __restrict__ vbuf) {
  __shared__ unsigned short sA[64 * 512];   // 64 KB, XOR-swizzled bf16 A tile

  const int t  = threadIdx.x;
  const int r0 = blockIdx.x * 64;

  // stage: states[64][512] f32 -> bf16 swizzled LDS
  {
    const float* gS = states + (size_t)r0 * SDIM;
#pragma unroll
    for (int it = 0; it < 16; it++) {
      int idx = it * 512 + t;          // float4 index, 8192 total
      int row = idx >> 7;              // 128 float4 per row
      int c4  = idx & 127;
      float4 v = ((const float4*)gS)[idx];
      int byte = (row * 1024 + c4 * 8) ^ ((row & 7) << 4);
      *(short4v*)((char*)sA + byte) = cvt4(v);
    }
  }
  __syncthreads();

  const int wave = t >> 6, lane = t & 63;
  const int wr = wave >> 2;       // 0..1
  const int wc = wave & 3;        // 0..3
  const int lrow = lane & 15, lk = lane >> 4;
  const int colbase = wc * 160;

  const unsigned short* bp[10];
#pragma unroll
  for (int f = 0; f < 10; f++)
    bp[f] = W0cat + (size_t)(colbase + f * 16 + lrow) * SDIM + 8 * lk;

  f32x4 acc[2][10];
#pragma unroll
  for (int i = 0; i < 2; i++)
#pragma unroll
    for (int f = 0; f < 10; f++) acc[i][f] = (f32x4){0.f, 0.f, 0.f, 0.f};

  short8v bcur[10], bnxt[10];
#pragma unroll
  for (int f = 0; f < 10; f++) bcur[f] = *(const short8v*)(bp[f]);

#pragma unroll 1
  for (int ks = 0; ks < 16; ks++) {
    if (ks < 15) {
#pragma unroll
      for (int f = 0; f < 10; f++) bnxt[f] = *(const short8v*)(bp[f] + (ks + 1) * 32);
    }
    short8v af[2];
#pragma unroll
    for (int i = 0; i < 2; i++) {
      int row = wr * 32 + i * 16 + lrow;
      int byte = (row * 1024 + ks * 64 + lk * 16) ^ ((row & 7) << 4);
      af[i] = *(const short8v*)((const char*)sA + byte);
    }
#pragma unroll
    for (int f = 0; f < 10; f++)
#pragma unroll
      for (int i = 0; i < 2; i++)
        acc[i][f] = __builtin_amdgcn_mfma_f32_16x16x32_bf16(af[i], bcur[f], acc[i][f], 0, 0, 0);
    if (ks < 15) {
#pragma unroll
      for (int f = 0; f < 10; f++) bcur[f] = bnxt[f];
    }
  }

  // epilogue: heads by column range
  float vs[2][4];
#pragma unroll
  for (int i = 0; i < 2; i++)
#pragma unroll
    for (int rr = 0; rr < 4; rr++) vs[i][rr] = 0.f;

#pragma unroll
  for (int f = 0; f < 10; f++) {
    int cb = colbase + f * 16;      // wave-uniform
    int col = cb + lrow;
#pragma unroll
    for (int i = 0; i < 2; i++) {
      if (cb < 512) {
        float bv = (cb < 256) ? b1_0[col] : bf_0[col - 256];
#pragma unroll
        for (int rr = 0; rr < 4; rr++) {
          int grow = r0 + wr * 32 + i * 16 + lk * 4 + rr;
          hcat[(size_t)grow * SDIM + col] = f2bf(fmaxf(acc[i][f][rr] + bv, 0.f));
        }
      } else if (cb < 576) {
        int e = col - 512;
        float bv = hb_b[e];
#pragma unroll
        for (int rr = 0; rr < 4; rr++) {
          int grow = r0 + wr * 32 + i * 16 + lk * 4 + rr;
          b1buf[(size_t)grow * EDIM + e] = acc[i][f][rr] + bv;
        }
      } else {
        int e = col - 576;
        float bv = v0_b[e], wv = v2_w[e];
#pragma unroll
        for (int rr = 0; rr < 4; rr++)
          vs[i][rr] = fmaf(fmaxf(acc[i][f][rr] + bv, 0.f), wv, vs[i][rr]);
      }
    }
  }
  if (wc == 3) {
#pragma unroll
    for (int i = 0; i < 2; i++)
#pragma unroll
      for (int rr = 0; rr < 4; rr++) {
        float v = vs[i][rr];
#pragma unroll
        for (int m = 1; m < 16; m <<= 1) v += __shfl_xor(v, m, 64);
        if (lrow == 0) vbuf[r0 + wr * 32 + i * 16 + lk * 4 + rr] = v;
      }
  }
}

// ---------------- GEMM2: fused hypernet-2 + mix, LDS dbuf B ----------------
__global__ __launch_bounds__(256, 2) void qmix_gemm2(
    const unsigned short* __restrict__ hcat, const unsigned short* __restrict__ w12b,
    const unsigned short* __restrict__ wf2b, const float* __restrict__ agent_qs,
    const float* __restrict__ b1_2, const float* __restrict__ bf_2,
    const float* __restrict__ b1buf, const float* __restrict__ vbuf,
    const float* __restrict__ v2_b, float* __restrict__ out) {
  const int t    = threadIdx.x;
  const int r0   = blockIdx.x * 64;
  const int wave = t >> 6;
  const int lane = t & 63;
  const int wr = wave >> 1, wc = wave & 1;
  const int lrow = lane & 15, lk = lane >> 4;

  __shared__ unsigned short bb[2][16384];   // 2 x 32 KB, swizzled B tiles
  __shared__ float q_lds[64 * 33];
  __shared__ float ypart[2][64];

  // ---- prologue: issue agent-0 B loads, q stage, A-fragment hoist ----
  short8v sreg[8];
#pragma unroll
  for (int rd = 0; rd < 8; rd++)
    sreg[rd] = *(const short8v*)(w12b + rd * 2048 + t * 8);   // agent 0

  {
    const float4* gq = (const float4*)(agent_qs + (size_t)r0 * NAG);
#pragma unroll
    for (int v = 0; v < 2; v++) {
      int idx = v * 256 + t;
      float4 qv = gq[idx];
      int row = idx >> 3, c4 = (idx & 7) * 4;
      q_lds[row * 33 + c4 + 0] = qv.x;
      q_lds[row * 33 + c4 + 1] = qv.y;
      q_lds[row * 33 + c4 + 2] = qv.z;
      q_lds[row * 33 + c4 + 3] = qv.w;
    }
  }

  short8v afr[2][8];
#pragma unroll
  for (int i = 0; i < 2; i++) {
    int grow = r0 + wr * 32 + i * 16 + lrow;
#pragma unroll
    for (int kf = 0; kf < 8; kf++)
      afr[i][kf] = *(const short8v*)(hcat + (size_t)grow * SDIM + kf * 32 + 8 * lk);
  }

  // write agent-0 stage into buf 0 (swizzled)
#pragma unroll
  for (int rd = 0; rd < 8; rd++) {
    int L = rd * 4096 + t * 16;
    int byte = L ^ (((L >> 9) & 7) << 4);
    *(short8v*)((char*)bb[0] + byte) = sreg[rd];
  }
  __syncthreads();

  f32x4 hac[2][2];
#pragma unroll
  for (int i = 0; i < 2; i++)
#pragma unroll
    for (int j = 0; j < 2; j++) hac[i][j] = (f32x4){0.f, 0.f, 0.f, 0.f};

#pragma unroll 1
  for (int a = 0; a < NAG; a++) {
    const int cur = a & 1;
    if (a < NAG - 1) {
      const unsigned short* src = w12b + (size_t)(a + 1) * 16384;
#pragma unroll
      for (int rd = 0; rd < 8; rd++)
        sreg[rd] = *(const short8v*)(src + rd * 2048 + t * 8);
    }

    f32x4 T[2][2];
#pragma unroll
    for (int i = 0; i < 2; i++)
#pragma unroll
      for (int j = 0; j < 2; j++) T[i][j] = (f32x4){0.f, 0.f, 0.f, 0.f};
#pragma unroll
    for (int kf = 0; kf < 8; kf++) {
      short8v bfv[2];
#pragma unroll
      for (int j = 0; j < 2; j++) {
        int row = wc * 32 + j * 16 + lrow;
        int L = row * 512 + kf * 64 + lk * 16;
        int byte = L ^ ((row & 7) << 4);
        bfv[j] = *(const short8v*)((const char*)bb[cur] + byte);
      }
#pragma unroll
      for (int i = 0; i < 2; i++)
#pragma unroll
        for (int j = 0; j < 2; j++)
          T[i][j] = __builtin_amdgcn_mfma_f32_16x16x32_bf16(afr[i][kf], bfv[j], T[i][j], 0, 0, 0);
    }

    float bbias[2];
#pragma unroll
    for (int j = 0; j < 2; j++) bbias[j] = b1_2[a * 64 + wc * 32 + j * 16 + lrow];
    float qv[2][4];
#pragma unroll
    for (int i = 0; i < 2; i++)
#pragma unroll
      for (int r = 0; r < 4; r++)
        qv[i][r] = q_lds[(wr * 32 + i * 16 + lk * 4 + r) * 33 + a];
#pragma unroll
    for (int i = 0; i < 2; i++)
#pragma unroll
      for (int j = 0; j < 2; j++)
#pragma unroll
        for (int r = 0; r < 4; r++)
          hac[i][j][r] = fmaf(qv[i][r], fabsf(T[i][j][r] + bbias[j]), hac[i][j][r]);

    if (a < NAG - 1) {
#pragma unroll
      for (int rd = 0; rd < 8; rd++) {
        int L = rd * 4096 + t * 16;
        int byte = L ^ (((L >> 9) & 7) << 4);
        *(short8v*)((char*)bb[cur ^ 1] + byte) = sreg[rd];
      }
    }
    __syncthreads();
  }

  // wfin = |hf @ wf_2^T + bf_2|
  f32x4 wfa[2][2];
#pragma unroll
  for (int i = 0; i < 2; i++)
#pragma unroll
    for (int j = 0; j < 2; j++) wfa[i][j] = (f32x4){0.f, 0.f, 0.f, 0.f};
#pragma unroll
  for (int kf = 0; kf < 8; kf++) {
    short8v af2[2], bf2v[2];
#pragma unroll
    for (int i = 0; i < 2; i++) {
      int grow = r0 + wr * 32 + i * 16 + lrow;
      af2[i] = *(const short8v*)(hcat + (size_t)grow * SDIM + 256 + kf * 32 + 8 * lk);
    }
#pragma unroll
    for (int j = 0; j < 2; j++) {
      int wrow = wc * 32 + j * 16 + lrow;
      bf2v[j] = *(const short8v*)(wf2b + (size_t)wrow * HD + kf * 32 + 8 * lk);
    }
#pragma unroll
    for (int i = 0; i < 2; i++)
#pragma unroll
      for (int j = 0; j < 2; j++)
        wfa[i][j] = __builtin_amdgcn_mfma_f32_16x16x32_bf16(af2[i], bf2v[j], wfa[i][j], 0, 0, 0);
  }

  float ys[8];
#pragma unroll
  for (int x = 0; x < 8; x++) ys[x] = 0.f;
#pragma unroll
  for (int i = 0; i < 2; i++) {
#pragma unroll
    for (int r = 0; r < 4; r++) {
      int row_l = wr * 32 + i * 16 + lk * 4 + r;
      int grow = r0 + row_l;
#pragma unroll
      for (int j = 0; j < 2; j++) {
        int e = wc * 32 + j * 16 + lrow;
        float pre = hac[i][j][r] + b1buf[(size_t)grow * EDIM + e];
        float h = pre > 0.f ? pre : expm1f(pre);
        float wf = fabsf(wfa[i][j][r] + bf_2[e]);
        ys[i * 4 + r] = fmaf(h, wf, ys[i * 4 + r]);
      }
    }
  }
#pragma unroll
  for (int m = 1; m < 16; m <<= 1)
#pragma unroll
    for (int x = 0; x < 8; x++) ys[x] += __shfl_xor(ys[x], m, 64);
  if (lrow == 0) {
#pragma unroll
    for (int i = 0; i < 2; i++)
#pragma unroll
      for (int r = 0; r < 4; r++)
        ypart[wc][wr * 32 + i * 16 + lk * 4 + r] = ys[i * 4 + r];
  }
  __syncthreads();
  if (t < 64) {
    int grow = r0 + t;
    out[grow] = ypart[0][t] + ypart[1][t] + vbuf[grow] + v2_b[0];
  }
}

extern "C" void kernel_launch(void* const* d_in, const int* in_sizes, int n_in,
                              void* d_out, int out_size, void* d_ws, size_t ws_size,
                              hipStream_t stream) {
  const float* agent_qs = (const float*)d_in[0];
  const float* states   = (const float*)d_in[1];
  const float* w1_0 = (const float*)d_in[2];
  const float* b1_0 = (const float*)d_in[3];
  const float* w1_2 = (const float*)d_in[4];
  const float* b1_2 = (const float*)d_in[5];
  const float* wf_0 = (const float*)d_in[6];
  const float* bf_0 = (const float*)d_in[7];
  const float* wf_2 = (const float*)d_in[8];
  const float* bf_2 = (const float*)d_in[9];
  const float* hb_w = (const float*)d_in[10];
  const float* hb_b = (const float*)d_in[11];
  const float* v0_w = (const float*)d_in[12];
  const float* v0_b = (const float*)d_in[13];
  const float* v2_w = (const float*)d_in[14];
  const float* v2_b = (const float*)d_in[15];

  char* ws = (char*)d_ws;
  unsigned short* hcat  = (unsigned short*)ws;                  // 33,554,432 B
  float*          b1buf = (float*)(ws + 33554432);              //  8,388,608 B
  float*          vbuf  = (float*)(ws + 41943040);              //    131,072 B
  unsigned short* W0cat = (unsigned short*)(ws + 42074112);     //    655,360 B
  unsigned short* w12b  = (unsigned short*)(ws + 42729472);     //  1,048,576 B
  unsigned short* wf2b  = (unsigned short*)(ws + 43778048);     //     32,768 B

  qmix_convert<<<3392, 256, 0, stream>>>(w1_0, wf_0, hb_w, v0_w, w1_2, wf_2, W0cat, w12b, wf2b);
  qmix_gemm1<<<512, 512, 0, stream>>>(states, W0cat, b1_0, bf_0, hb_b, v0_b, v2_w,
                                      hcat, b1buf, vbuf);
  qmix_gemm2<<<512, 256, 0, stream>>>(hcat, w12b, wf2b, agent_qs, b1_2, bf_2, b1buf, vbuf,
                                      v2_b, (float*)d_out);
}

// Round 5
// 124.779 us; speedup vs baseline: 27.0536x; 1.2595x over previous
//
#include <hip/hip_runtime.h>

// QMixer — round 5: single fused kernel, conservative sync.
// (Round 4 failed post-timing revalidation — timing-dependent race. The only
//  structure not shared with a replay-proven round was the split-K staging
//  overlap; removed here. All other phases identical to round 4.)
// Per block (64 rows, 512 threads, ~157 KB LDS):
//   phase0: issue ALL state/q global loads, prefetch gemm1 B ks=0,1;
//           write full states tile -> bf16 swizzled LDS; barrier.
//   gemm1:  [64,512] x [512,640]^T, waves 1x8 (wave tile 64x80),
//           2-deep register B prefetch from L2.
//   epi1:   heads (relu h1|hf -> back into SAME LDS tile, b1 -> b1t, v head);
//           hcat/b1buf/vbuf never touch HBM.
//   gemm2:  per-agent w1_2 tiles LDS-double-buffered (reg-stage T14),
//           fused |.|, q-contraction; waves 4x2 over 64x64.
//   wf:     |hf@wf_2^T+bf_2|, elu-mix epilogue, out write.

#define SDIM 512
#define HD   256
#define EDIM 64
#define NAG  32

typedef short short8v __attribute__((ext_vector_type(8)));
typedef short short4v __attribute__((ext_vector_type(4)));
typedef float f32x4  __attribute__((ext_vector_type(4)));

__device__ __forceinline__ unsigned short f2bf(float f) {
  unsigned int u = __float_as_uint(f);
  unsigned int r = (u + 0x7FFFu + ((u >> 16) & 1u)) >> 16;
  return (unsigned short)r;
}

__device__ __forceinline__ short4v cvt4(float4 a) {
  short4v r;
  r[0] = (short)f2bf(a.x); r[1] = (short)f2bf(a.y);
  r[2] = (short)f2bf(a.z); r[3] = (short)f2bf(a.w);
  return r;
}

// ---------------- convert weights to bf16 ----------------
// W0cat [640][512] = w1_0(256) | wf_0(256) | hb_w(64) | v0_w(64)
// w12b [2048][256]; wf2b [64][256]
__global__ void qmix_convert(const float* __restrict__ w1_0, const float* __restrict__ wf_0,
                             const float* __restrict__ hb_w, const float* __restrict__ v0_w,
                             const float* __restrict__ w1_2, const float* __restrict__ wf_2,
                             unsigned short* __restrict__ W0cat, unsigned short* __restrict__ w12b,
                             unsigned short* __restrict__ wf2b) {
  int i = blockIdx.x * 256 + threadIdx.x;
  if (i < 327680) {
    float v;
    if (i < 131072)      v = w1_0[i];
    else if (i < 262144) v = wf_0[i - 131072];
    else if (i < 294912) v = hb_w[i - 262144];
    else                 v = v0_w[i - 294912];
    W0cat[i] = f2bf(v);
  } else if (i < 851968) {
    w12b[i - 327680] = f2bf(w1_2[i - 327680]);
  } else if (i < 868352) {
    wf2b[i - 851968] = f2bf(wf_2[i - 851968]);
  }
}

// ---------------- fused main kernel ----------------
__global__ __launch_bounds__(512, 2) void qmix_main(
    const float* __restrict__ agent_qs, const float* __restrict__ states,
    const unsigned short* __restrict__ W0cat, const unsigned short* __restrict__ w12b,
    const unsigned short* __restrict__ wf2b,
    const float* __restrict__ b1_0, const float* __restrict__ bf_0,
    const float* __restrict__ hb_b, const float* __restrict__ v0_b,
    const float* __restrict__ v2_w, const float* __restrict__ b1_2,
    const float* __restrict__ bf_2, const float* __restrict__ v2_b,
    float* __restrict__ out)
{
  __shared__ unsigned short sA[64 * 512];      // 64 KB: states, then h1|hf (swizzled)
  __shared__ unsigned short bb[2][16384];      // 64 KB: gemm2 B dbuf (swizzled)
  __shared__ float b1t[64 * 65];               // 16.6 KB
  __shared__ float q_lds[64 * 33];             // 8.4 KB
  __shared__ float vrow[64];
  __shared__ float ypart[2][64];

  const int t    = threadIdx.x;
  const int r0   = blockIdx.x * 64;
  const int wave = t >> 6, lane = t & 63;
  const int lrow = lane & 15, lk = lane >> 4;

  // ---- phase 0: issue ALL global loads up front ----
  const float4* gS4 = (const float4*)(states + (size_t)r0 * SDIM);
  float4 L[16];
#pragma unroll
  for (int it = 0; it < 16; it++) L[it] = gS4[it * 512 + t];
  float4 qreg = ((const float4*)(agent_qs + (size_t)r0 * NAG))[t];

  // gemm1 B prefetch for ks=0,1 (L2-resident weights)
  const int colbase = wave * 80;
  const unsigned short* bp[5];
#pragma unroll
  for (int f = 0; f < 5; f++)
    bp[f] = W0cat + (size_t)(colbase + f * 16 + lrow) * SDIM + 8 * lk;
  short8v bregs[2][5];
#pragma unroll
  for (int f = 0; f < 5; f++) bregs[0][f] = *(const short8v*)(bp[f]);
#pragma unroll
  for (int f = 0; f < 5; f++) bregs[1][f] = *(const short8v*)(bp[f] + 32);

  // write FULL states tile (both halves) + q tile, then one barrier
#pragma unroll
  for (int it = 0; it < 16; it++) {
    int idx = it * 512 + t;
    int row = idx >> 7, c4 = idx & 127;
    int byte = (row * 1024 + c4 * 8) ^ ((row & 7) << 4);
    *(short4v*)((char*)sA + byte) = cvt4(L[it]);
  }
  {
    int qrow = t >> 3, qc = (t & 7) * 4;
    q_lds[qrow * 33 + qc + 0] = qreg.x;
    q_lds[qrow * 33 + qc + 1] = qreg.y;
    q_lds[qrow * 33 + qc + 2] = qreg.z;
    q_lds[qrow * 33 + qc + 3] = qreg.w;
  }
  __syncthreads();

  // ---- gemm1: acc[4][5], wave tile 64 rows x 80 cols ----
  f32x4 acc[4][5];
#pragma unroll
  for (int i = 0; i < 4; i++)
#pragma unroll
    for (int f = 0; f < 5; f++) acc[i][f] = (f32x4){0.f, 0.f, 0.f, 0.f};

#pragma unroll
  for (int ks = 0; ks < 16; ks++) {
    const int p = ks & 1;
    short8v af[4];
#pragma unroll
    for (int i = 0; i < 4; i++) {
      int row = i * 16 + lrow;
      int byte = (row * 1024 + ks * 64 + lk * 16) ^ ((row & 7) << 4);
      af[i] = *(const short8v*)((const char*)sA + byte);
    }
#pragma unroll
    for (int f = 0; f < 5; f++)
#pragma unroll
      for (int i = 0; i < 4; i++)
        acc[i][f] = __builtin_amdgcn_mfma_f32_16x16x32_bf16(af[i], bregs[p][f], acc[i][f], 0, 0, 0);
    if (ks < 14) {
#pragma unroll
      for (int f = 0; f < 5; f++) bregs[p][f] = *(const short8v*)(bp[f] + (ks + 2) * 32);
    }
  }

  __syncthreads();   // all sA reads done; safe to overwrite with h-tile

  // ---- gemm1 epilogue: heads by column range, h written back into sA ----
  {
    float vs[4][4];
#pragma unroll
    for (int i = 0; i < 4; i++)
#pragma unroll
      for (int rr = 0; rr < 4; rr++) vs[i][rr] = 0.f;

#pragma unroll
    for (int f = 0; f < 5; f++) {
      int cb  = colbase + f * 16;    // wave-uniform
      int col = cb + lrow;
      if (cb < 512) {
        float bv = (cb < 256) ? b1_0[col] : bf_0[col - 256];
#pragma unroll
        for (int i = 0; i < 4; i++)
#pragma unroll
          for (int rr = 0; rr < 4; rr++) {
            int row = i * 16 + lk * 4 + rr;
            float v = fmaxf(acc[i][f][rr] + bv, 0.f);
            int byte = (row * 1024 + col * 2) ^ ((row & 7) << 4);
            *(unsigned short*)((char*)sA + byte) = f2bf(v);
          }
      } else if (cb < 576) {
        int e = col - 512;
        float bv = hb_b[e];
#pragma unroll
        for (int i = 0; i < 4; i++)
#pragma unroll
          for (int rr = 0; rr < 4; rr++) {
            int row = i * 16 + lk * 4 + rr;
            b1t[row * 65 + e] = acc[i][f][rr] + bv;
          }
      } else {
        int e = col - 576;
        float bv = v0_b[e], wv = v2_w[e];
#pragma unroll
        for (int i = 0; i < 4; i++)
#pragma unroll
          for (int rr = 0; rr < 4; rr++)
            vs[i][rr] = fmaf(fmaxf(acc[i][f][rr] + bv, 0.f), wv, vs[i][rr]);
      }
    }
    if (colbase == 560) {    // wave 7 owns the v head
#pragma unroll
      for (int i = 0; i < 4; i++)
#pragma unroll
        for (int rr = 0; rr < 4; rr++) {
          float v = vs[i][rr];
#pragma unroll
          for (int m = 1; m < 16; m <<= 1) v += __shfl_xor(v, m, 64);
          if (lrow == 0) vrow[i * 16 + lk * 4 + rr] = v;
        }
    }
  }

  // ---- issue agent-0 B loads before the barrier (latency hidden) ----
  short8v sreg[4];
#pragma unroll
  for (int rd = 0; rd < 4; rd++)
    sreg[rd] = *(const short8v*)(w12b + rd * 4096 + t * 8);

  __syncthreads();   // h-tile, b1t, vrow visible

  // ---- gemm2: waves 4(row) x 2(col) over 64x64, per-agent LDS dbuf ----
  const int wr = wave >> 1;     // 0..3
  const int wc = wave & 1;      // 0..1

  // hoist A fragments (h1 rows, K=256) into registers
  short8v afr[8];
  {
    int row = wr * 16 + lrow;
#pragma unroll
    for (int kf = 0; kf < 8; kf++) {
      int byte = (row * 1024 + kf * 64 + lk * 16) ^ ((row & 7) << 4);
      afr[kf] = *(const short8v*)((const char*)sA + byte);
    }
  }

  // stage agent 0 into bb[0]
#pragma unroll
  for (int rd = 0; rd < 4; rd++) {
    int Lo = rd * 8192 + t * 16;
    int byte = Lo ^ (((Lo >> 9) & 7) << 4);
    *(short8v*)((char*)bb + byte) = sreg[rd];
  }
  __syncthreads();

  f32x4 hac[2];
  hac[0] = (f32x4){0.f, 0.f, 0.f, 0.f};
  hac[1] = (f32x4){0.f, 0.f, 0.f, 0.f};

#pragma unroll 1
  for (int a = 0; a < NAG; a++) {
    if (a < NAG - 1) {
      const unsigned short* src = w12b + (size_t)(a + 1) * 16384;
#pragma unroll
      for (int rd = 0; rd < 4; rd++)
        sreg[rd] = *(const short8v*)(src + rd * 4096 + t * 8);
    }
    const char* rbase = (const char*)bb + (a & 1) * 32768;

    f32x4 T[2];
    T[0] = (f32x4){0.f, 0.f, 0.f, 0.f};
    T[1] = (f32x4){0.f, 0.f, 0.f, 0.f};
#pragma unroll
    for (int kf = 0; kf < 8; kf++) {
      short8v bfv[2];
#pragma unroll
      for (int j = 0; j < 2; j++) {
        int e = wc * 32 + j * 16 + lrow;
        int Lo = e * 512 + kf * 64 + lk * 16;
        bfv[j] = *(const short8v*)(rbase + (Lo ^ ((e & 7) << 4)));
      }
#pragma unroll
      for (int j = 0; j < 2; j++)
        T[j] = __builtin_amdgcn_mfma_f32_16x16x32_bf16(afr[kf], bfv[j], T[j], 0, 0, 0);
    }

    float bbias[2];
#pragma unroll
    for (int j = 0; j < 2; j++) bbias[j] = b1_2[a * 64 + wc * 32 + j * 16 + lrow];
    float qv[4];
#pragma unroll
    for (int r = 0; r < 4; r++)
      qv[r] = q_lds[(wr * 16 + lk * 4 + r) * 33 + a];
#pragma unroll
    for (int j = 0; j < 2; j++)
#pragma unroll
      for (int r = 0; r < 4; r++)
        hac[j][r] = fmaf(qv[r], fabsf(T[j][r] + bbias[j]), hac[j][r]);

    if (a < NAG - 1) {
      char* wbase = (char*)bb + ((a & 1) ^ 1) * 32768;
#pragma unroll
      for (int rd = 0; rd < 4; rd++) {
        int Lo = rd * 8192 + t * 16;
        *(short8v*)(wbase + (Lo ^ (((Lo >> 9) & 7) << 4))) = sreg[rd];
      }
    }
    __syncthreads();
  }

  // ---- wf: |hf @ wf_2^T + bf_2| (hf = sA bytes 512..1023 per row) ----
  f32x4 wfa[2];
  wfa[0] = (f32x4){0.f, 0.f, 0.f, 0.f};
  wfa[1] = (f32x4){0.f, 0.f, 0.f, 0.f};
  {
    int row = wr * 16 + lrow;
#pragma unroll
    for (int kf = 0; kf < 8; kf++) {
      int byte = (row * 1024 + 512 + kf * 64 + lk * 16) ^ ((row & 7) << 4);
      short8v af2 = *(const short8v*)((const char*)sA + byte);
      short8v bf2v[2];
#pragma unroll
      for (int j = 0; j < 2; j++) {
        int e = wc * 32 + j * 16 + lrow;
        bf2v[j] = *(const short8v*)(wf2b + (size_t)e * HD + kf * 32 + 8 * lk);
      }
#pragma unroll
      for (int j = 0; j < 2; j++)
        wfa[j] = __builtin_amdgcn_mfma_f32_16x16x32_bf16(af2, bf2v[j], wfa[j], 0, 0, 0);
    }
  }

  // ---- final epilogue: elu(hid+b1)*wfin, reduce over e ----
  {
    float ys[4];
#pragma unroll
    for (int r = 0; r < 4; r++) ys[r] = 0.f;
#pragma unroll
    for (int r = 0; r < 4; r++) {
      int row = wr * 16 + lk * 4 + r;
#pragma unroll
      for (int j = 0; j < 2; j++) {
        int e = wc * 32 + j * 16 + lrow;
        float pre = hac[j][r] + b1t[row * 65 + e];
        float h = pre > 0.f ? pre : expm1f(pre);
        float wfv = fabsf(wfa[j][r] + bf_2[e]);
        ys[r] = fmaf(h, wfv, ys[r]);
      }
    }
#pragma unroll
    for (int m = 1; m < 16; m <<= 1)
#pragma unroll
      for (int r = 0; r < 4; r++) ys[r] += __shfl_xor(ys[r], m, 64);
    if (lrow == 0) {
#pragma unroll
      for (int r = 0; r < 4; r++)
        ypart[wc][wr * 16 + lk * 4 + r] = ys[r];
    }
  }
  __syncthreads();
  if (t < 64) {
    out[r0 + t] = ypart[0][t] + ypart[1][t] + vrow[t] + v2_b[0];
  }
}

extern "C" void kernel_launch(void* const* d_in, const int* in_sizes, int n_in,
                              void* d_out, int out_size, void* d_ws, size_t ws_size,
                              hipStream_t stream) {
  const float* agent_qs = (const float*)d_in[0];
  const float* states   = (const float*)d_in[1];
  const float* w1_0 = (const float*)d_in[2];
  const float* b1_0 = (const float*)d_in[3];
  const float* w1_2 = (const float*)d_in[4];
  const float* b1_2 = (const float*)d_in[5];
  const float* wf_0 = (const float*)d_in[6];
  const float* bf_0 = (const float*)d_in[7];
  const float* wf_2 = (const float*)d_in[8];
  const float* bf_2 = (const float*)d_in[9];
  const float* hb_w = (const float*)d_in[10];
  const float* hb_b = (const float*)d_in[11];
  const float* v0_w = (const float*)d_in[12];
  const float* v0_b = (const float*)d_in[13];
  const float* v2_w = (const float*)d_in[14];
  const float* v2_b = (const float*)d_in[15];

  char* ws = (char*)d_ws;
  unsigned short* W0cat = (unsigned short*)ws;                 //   655,360 B
  unsigned short* w12b  = (unsigned short*)(ws + 655360);      // 1,048,576 B
  unsigned short* wf2b  = (unsigned short*)(ws + 1703936);     //    32,768 B

  qmix_convert<<<3392, 256, 0, stream>>>(w1_0, wf_0, hb_w, v0_w, w1_2, wf_2,
                                         W0cat, w12b, wf2b);
  qmix_main<<<512, 512, 0, stream>>>(agent_qs, states, W0cat, w12b, wf2b,
                                     b1_0, bf_0, hb_b, v0_b, v2_w, b1_2, bf_2, v2_b,
                                     (float*)d_out);
}